// Round 1
// baseline (183.855 us; speedup 1.0000x reference)
//
#include <hip/hip_runtime.h>
#include <math.h>

#define N_NODES 100000
#define N_EDGES 3200000
#define EPS_F 1e-6f

// ---- fused gather: hybrid LDS (80000 bf16 nodes = 160 KB) + L2 spill ----
#define GS_N     80000
#define GNB      256                    // 1 block/CU (160 KB LDS)
#define GB_PAIRS (N_EDGES / 2 / GNB)    // 6250 pairs per block

// ---- scatter: 3 slices of fp32 bins (133,344 B LDS) ----
#define SLICE_N 33336                   // 3*33336 = 100008 >= N_NODES, %8==0
#define NSLICE  3
#define NCHUNK  64
#define C_PAIRS (N_EDGES / 2 / NCHUNK)  // 25000 pairs per chunk (400 KB)
#define SBATCH  16

#define NVARB   6250                    // prep blocks (1 pair/thread, exact)
#define NKCLB   391                     // kcl blocks

// ws layout (4-byte words) — 51.3 MB total (<= proven 51.7 MB budget)
//   PK_OFF   : u64 pack[N_EDGES]  lo = src | dst<<17 ; hi = dst>>15 | cur<<2
//              prep writes ids (cur=0), gather rewrites hi with cur (bf16)
//   PART_OFF : partials[NCHUNK][N_NODES]  (25.6 MB)
//   W_OFF    : bf16 w[e] = sigmoid(lg)/(imp+eps)  -- ALIASES PART (dead by scatter)
//   V_OFF    : packed fp32 v[N_NODES]              -- ALIASES PART (dead by scatter)
//   VARP_OFF : per-block float4 {s0,s1,q0,q1}[NVARB]
//   KCLP_OFF : per-block kcl partial [NKCLB]
#define PK_OFF    64
#define PART_OFF  (PK_OFF + 2 * N_EDGES)         // 6,400,064
#define W_OFF     PART_OFF                        // 1.6M words, dead before scatter
#define V_OFF     (PART_OFF + N_EDGES / 2)        // 0.1M words, dead before scatter
#define VARP_OFF  (PART_OFF + NCHUNK * N_NODES)   // 12,800,064
#define KCLP_OFF  (VARP_OFF + 4 * NVARB)
#define WS_FLOATS (KCLP_OFF + NKCLB + 64)

__device__ __forceinline__ float wave_reduce(float v) {
    #pragma unroll
    for (int off = 32; off > 0; off >>= 1) v += __shfl_down(v, off, 64);
    return v;
}

__device__ __forceinline__ void fadd_agent(float* p, float v) {
    unsafeAtomicAdd(p, v);   // fallback path only
}

// bf16 pack/unpack (RNE)
__device__ __forceinline__ unsigned short f2bf(float f) {
    unsigned u = __float_as_uint(f);
    unsigned r = ((u >> 16) & 1u) + 0x7FFFu;
    return (unsigned short)((u + r) >> 16);
}
__device__ __forceinline__ float bf2f(unsigned short h) {
    return __uint_as_float(((unsigned)h) << 16);
}

// ---------------- pass 1: prep = pack ids + varsum + w + packv ----------------
__global__ __launch_bounds__(256) void prep_kernel(
    const float*  __restrict__ nf,
    const void*   __restrict__ eidx,
    const float*  __restrict__ logits,
    const float2* __restrict__ params,
    float*        __restrict__ ws)
{
    __shared__ float red[4][4];
    const int* i32 = (const int*)eidx;

    // int64 values < 2^31 have zero hi-words at every odd int32 slot;
    // int32 has random node ids there (16 zeros ~ impossible).
    int any = 0;
    #pragma unroll
    for (int k = 1; k < 32; k += 2) any |= i32[k];
    const bool is32 = (any != 0);

    const int t = blockIdx.x * blockDim.x + threadIdx.x;   // pair index, exact

    int2 sp, dp;
    if (is32) {
        sp = ((const int2*)i32)[t];
        dp = ((const int2*)(i32 + N_EDGES))[t];
    } else {
        const int4 a = ((const int4*)i32)[t];                  // 2x int64 src
        const int4 b = ((const int4*)(i32 + 2 * N_EDGES))[t];  // 2x int64 dst
        sp = make_int2(a.x, a.z);
        dp = make_int2(b.x, b.z);
    }
    // pack: lo = src | dst<<17 ; hi = dst>>15 (cur filled by gather)
    int4 pk;
    pk.x = (int)((unsigned)sp.x | ((unsigned)dp.x << 17));
    pk.y = (int)(((unsigned)dp.x) >> 15);
    pk.z = (int)((unsigned)sp.y | ((unsigned)dp.y << 17));
    pk.w = (int)(((unsigned)dp.y) >> 15);
    ((int4*)(ws + PK_OFF))[t] = pk;

    const float4 pp = ((const float4*)params)[t];
    const float2 lg = ((const float2*)logits)[t];
    const float w0 = (1.0f / (1.0f + __expf(-lg.x))) / (pp.x + pp.y + EPS_F);
    const float w1 = (1.0f / (1.0f + __expf(-lg.y))) / (pp.z + pp.w + EPS_F);
    ((unsigned*)(ws + W_OFF))[t] = (unsigned)f2bf(w0) | ((unsigned)f2bf(w1) << 16);

    if (t < N_NODES) ws[V_OFF + t] = nf[t * 4];

    float s0 = pp.x + pp.z;
    float s1 = pp.y + pp.w;
    float q0 = pp.x * pp.x + pp.z * pp.z;
    float q1 = pp.y * pp.y + pp.w * pp.w;

    s0 = wave_reduce(s0); s1 = wave_reduce(s1);
    q0 = wave_reduce(q0); q1 = wave_reduce(q1);

    const int wid = threadIdx.x >> 6;
    if ((threadIdx.x & 63) == 0) {
        red[wid][0] = s0; red[wid][1] = s1; red[wid][2] = q0; red[wid][3] = q1;
    }
    __syncthreads();
    if (threadIdx.x == 0) {
        float4 o;
        o.x = red[0][0] + red[1][0] + red[2][0] + red[3][0];
        o.y = red[0][1] + red[1][1] + red[2][1] + red[3][1];
        o.z = red[0][2] + red[1][2] + red[2][2] + red[3][2];
        o.w = red[0][3] + red[1][3] + red[2][3] + red[3][3];
        ((float4*)(ws + VARP_OFF))[blockIdx.x] = o;
    }
}

// ---------------- pass 2: fused gather — cur = |v[src]-v[dst]|*w, in-place ----------------
// 80000 bf16 nodes in 160 KB LDS; ids >= GS_N read fp32 from the 80 KB
// L2-hot tail of the v table. One pass replaces the old S+D slice passes.
__global__ __launch_bounds__(1024) void gather_kernel(float* __restrict__ ws)
{
    __shared__ unsigned vlds32[GS_N / 2];     // 160,000 B

    const float*  vtab = ws + V_OFF;
    const float2* v2   = (const float2*)vtab;
    for (int j = threadIdx.x; j < GS_N / 2; j += 1024) {
        const float2 f = v2[j];
        vlds32[j] = (unsigned)f2bf(f.x) | ((unsigned)f2bf(f.y) << 16);
    }
    __syncthreads();
    const unsigned short* vl = (const unsigned short*)vlds32;

    int4*           pk = (int4*)(ws + PK_OFF);
    const unsigned* ww = (const unsigned*)(ws + W_OFF);

    const int p0   = blockIdx.x * GB_PAIRS;
    const int p1   = p0 + GB_PAIRS;
    const int base = p0 + (int)threadIdx.x;

    int4     q[8];
    unsigned wv[8];
    #pragma unroll
    for (int k = 0; k < 8; ++k) {
        int p = base + k * 1024;
        p = (p < p1) ? p : (p1 - 1);   // clamp: loads stay unconditional
        q[k]  = pk[p];
        wv[k] = ww[p];
    }
    #pragma unroll
    for (int k = 0; k < 8; ++k) {
        const int p = base + k * 1024;
        if (p < p1) {
            const unsigned lo0 = (unsigned)q[k].x, hi0 = (unsigned)q[k].y;
            const unsigned lo1 = (unsigned)q[k].z, hi1 = (unsigned)q[k].w;
            const int s0 = (int)(lo0 & 0x1FFFFu);
            const int d0 = (int)((lo0 >> 17) | ((hi0 & 3u) << 15));
            const int s1 = (int)(lo1 & 0x1FFFFu);
            const int d1 = (int)((lo1 >> 17) | ((hi1 & 3u) << 15));
            const float vs0 = (s0 < GS_N) ? bf2f(vl[s0]) : vtab[s0];
            const float vd0 = (d0 < GS_N) ? bf2f(vl[d0]) : vtab[d0];
            const float vs1 = (s1 < GS_N) ? bf2f(vl[s1]) : vtab[s1];
            const float vd1 = (d1 < GS_N) ? bf2f(vl[d1]) : vtab[d1];
            const float c0 = fabsf(vs0 - vd0) * bf2f((unsigned short)(wv[k] & 0xFFFF));
            const float c1 = fabsf(vs1 - vd1) * bf2f((unsigned short)(wv[k] >> 16));
            q[k].y = (int)((hi0 & 3u) | ((unsigned)f2bf(c0) << 2));
            q[k].w = (int)((hi1 & 3u) | ((unsigned)f2bf(c1) << 2));
            pk[p] = q[k];
        }
    }
}

// ---------------- pass 3: LDS-binned scatter, 3 slices, 16-pair ILP ----------------
// 1 int4 load per pair (vs 3 loads before). Slice blocks of chunk c are
// blockIdx = c, c+64, c+128 -> all ≡ c (mod 8): same XCD, and the 8
// concurrent chunks/XCD total 3.2 MB < 4 MB L2 (was 8 MB at 8 slices).
__global__ __launch_bounds__(1024) void scatter_kernel(float* __restrict__ ws)
{
    __shared__ float bins[SLICE_N];   // 133,344 B

    const int c  = blockIdx.x & (NCHUNK - 1);
    const int s  = blockIdx.x >> 6;
    const unsigned lo = (unsigned)(s * SLICE_N);

    for (int j = threadIdx.x; j < SLICE_N / 4; j += 1024)
        ((float4*)bins)[j] = make_float4(0.f, 0.f, 0.f, 0.f);
    __syncthreads();

    const int4* pk = (const int4*)(ws + PK_OFF);

    const int p0 = c * C_PAIRS;
    const int p1 = p0 + C_PAIRS;

    for (int base = p0 + (int)threadIdx.x; base < p1; base += 1024 * SBATCH) {
        int4 q[SBATCH];
        #pragma unroll
        for (int k = 0; k < SBATCH; ++k) {
            int p = base + k * 1024;
            p = (p < p1) ? p : (p1 - 1);   // clamp: loads stay unconditional
            q[k] = pk[p];
        }
        #pragma unroll
        for (int k = 0; k < SBATCH; ++k) {
            const int p = base + k * 1024;
            if (p < p1) {
                const unsigned lo0 = (unsigned)q[k].x, hi0 = (unsigned)q[k].y;
                const unsigned lo1 = (unsigned)q[k].z, hi1 = (unsigned)q[k].w;
                const unsigned s0 = (lo0 & 0x1FFFFu) - lo;
                const unsigned d0 = ((lo0 >> 17) | ((hi0 & 3u) << 15)) - lo;
                const unsigned s1 = (lo1 & 0x1FFFFu) - lo;
                const unsigned d1 = ((lo1 >> 17) | ((hi1 & 3u) << 15)) - lo;
                const float c0 = bf2f((unsigned short)((hi0 >> 2) & 0xFFFFu));
                const float c1 = bf2f((unsigned short)((hi1 >> 2) & 0xFFFFu));
                if (d0 < SLICE_N) atomicAdd(&bins[d0],  c0);
                if (s0 < SLICE_N) atomicAdd(&bins[s0], -c0);
                if (d1 < SLICE_N) atomicAdd(&bins[d1],  c1);
                if (s1 < SLICE_N) atomicAdd(&bins[s1], -c1);
            }
        }
    }
    __syncthreads();

    const int n4 = ((int)(N_NODES - lo) < SLICE_N ? (int)(N_NODES - lo) : SLICE_N) / 4;
    float4* pt4 = (float4*)(ws + PART_OFF + (size_t)c * N_NODES + lo);
    for (int j = threadIdx.x; j < n4; j += 1024)
        pt4[j] = ((const float4*)bins)[j];
}

// ---------------- pass 4: merge partials, sum of squares (no atomics) ----------------
__global__ __launch_bounds__(256) void kcl_kernel(float* __restrict__ ws)
{
    __shared__ float red[4];
    const int i = blockIdx.x * blockDim.x + threadIdx.x;
    float acc = 0.f;
    if (i < N_NODES) {
        const float* p = ws + PART_OFF + i;
        float s = 0.f;
        #pragma unroll 8
        for (int c = 0; c < NCHUNK; ++c) s += p[(size_t)c * N_NODES];
        acc = s * s;
    }
    acc = wave_reduce(acc);
    if ((threadIdx.x & 63) == 0) red[threadIdx.x >> 6] = acc;
    __syncthreads();
    if (threadIdx.x == 0)
        ws[KCLP_OFF + blockIdx.x] = red[0] + red[1] + red[2] + red[3];
}

// ---------------- pass 5: final reduce of block partials ----------------
__global__ __launch_bounds__(1024) void final_kernel(
    const float* __restrict__ ws, float* __restrict__ out)
{
    __shared__ float red[16][5];
    float s0 = 0.f, s1 = 0.f, q0 = 0.f, q1 = 0.f, k = 0.f;

    const float4* vp = (const float4*)(ws + VARP_OFF);
    for (int i = threadIdx.x; i < NVARB; i += 1024) {
        const float4 v = vp[i];
        s0 += v.x; s1 += v.y; q0 += v.z; q1 += v.w;
    }
    for (int i = threadIdx.x; i < NKCLB; i += 1024) k += ws[KCLP_OFF + i];

    s0 = wave_reduce(s0); s1 = wave_reduce(s1);
    q0 = wave_reduce(q0); q1 = wave_reduce(q1);
    k  = wave_reduce(k);

    const int wid = threadIdx.x >> 6;
    if ((threadIdx.x & 63) == 0) {
        red[wid][0] = s0; red[wid][1] = s1; red[wid][2] = q0;
        red[wid][3] = q1; red[wid][4] = k;
    }
    __syncthreads();
    if (threadIdx.x == 0) {
        float a0 = 0.f, a1 = 0.f, a2 = 0.f, a3 = 0.f, a4 = 0.f;
        #pragma unroll
        for (int w = 0; w < 16; ++w) {
            a0 += red[w][0]; a1 += red[w][1]; a2 += red[w][2];
            a3 += red[w][3]; a4 += red[w][4];
        }
        const float n    = (float)N_EDGES;
        const float var0 = (a2 - a0 * a0 / n) / (n - 1.0f);
        const float var1 = (a3 - a1 * a1 / n) / (n - 1.0f);
        out[0] = a4 / (float)N_NODES + 0.5f * (var0 + var1);
    }
}

// ---------------- fallback (ws too small): agent-atomic scatter ----------------
#define FB_NODE_OFF 64
__global__ __launch_bounds__(256) void edge_kernel_fb(
    const float*  __restrict__ nf,
    const void*   __restrict__ eidx,
    const float*  __restrict__ logits,
    const float2* __restrict__ params,
    float*        __restrict__ ws)
{
    const int*       i32 = (const int*)eidx;
    const long long* i64 = (const long long*)eidx;
    int any = 0;
    #pragma unroll
    for (int k = 1; k < 32; k += 2) any |= i32[k];
    const bool is32 = (any != 0);

    float* node_sum = ws + FB_NODE_OFF;
    float* acc      = ws + 1;

    float s0 = 0.f, s1 = 0.f, q0 = 0.f, q1 = 0.f;
    const int tid    = blockIdx.x * blockDim.x + threadIdx.x;
    const int stride = gridDim.x * blockDim.x;
    for (int i = tid; i < N_EDGES; i += stride) {
        int src, dst;
        if (is32) { src = i32[i]; dst = i32[N_EDGES + i]; }
        else      { src = (int)i64[i]; dst = (int)i64[N_EDGES + i]; }
        const float2 ep = params[i];
        const float  p  = 1.0f / (1.0f + __expf(-logits[i]));
        const float cur = fabsf(nf[src * 4] - nf[dst * 4]) / (ep.x + ep.y + EPS_F) * p;
        fadd_agent(node_sum + dst,  cur);
        fadd_agent(node_sum + src, -cur);
        s0 += ep.x; s1 += ep.y; q0 += ep.x * ep.x; q1 += ep.y * ep.y;
    }
    s0 = wave_reduce(s0); s1 = wave_reduce(s1);
    q0 = wave_reduce(q0); q1 = wave_reduce(q1);
    if ((threadIdx.x & 63) == 0) {
        fadd_agent(acc + 0, s0); fadd_agent(acc + 1, s1);
        fadd_agent(acc + 2, q0); fadd_agent(acc + 3, q1);
    }
}

__global__ __launch_bounds__(256) void kcl_kernel_fb(float* __restrict__ ws)
{
    const float* node_sum = ws + FB_NODE_OFF;
    float acc = 0.f;
    const int tid    = blockIdx.x * blockDim.x + threadIdx.x;
    const int stride = gridDim.x * blockDim.x;
    for (int i = tid; i < N_NODES; i += stride) {
        const float v = node_sum[i];
        acc += v * v;
    }
    acc = wave_reduce(acc);
    if ((threadIdx.x & 63) == 0) fadd_agent(ws + 5, acc);
}

__global__ void final_kernel_fb(const float* __restrict__ ws, float* __restrict__ out)
{
    const float s0 = ws[1], s1 = ws[2], q0 = ws[3], q1 = ws[4], k = ws[5];
    const float n  = (float)N_EDGES;
    const float var0 = (q0 - s0 * s0 / n) / (n - 1.0f);
    const float var1 = (q1 - s1 * s1 / n) / (n - 1.0f);
    out[0] = k / (float)N_NODES + 0.5f * (var0 + var1);
}

extern "C" void kernel_launch(void* const* d_in, const int* in_sizes, int n_in,
                              void* d_out, int out_size, void* d_ws, size_t ws_size,
                              hipStream_t stream) {
    const float*  nf     = (const float*)d_in[0];
    const void*   eidx   = d_in[1];
    const float*  logits = (const float*)d_in[2];
    const float2* params = (const float2*)d_in[3];
    float* ws  = (float*)d_ws;
    float* out = (float*)d_out;

    const size_t need = (size_t)WS_FLOATS * sizeof(float);   // ~51.3 MB

    if (ws_size >= need) {
        prep_kernel<<<NVARB, 256, 0, stream>>>(nf, eidx, logits, params, ws);
        gather_kernel<<<GNB, 1024, 0, stream>>>(ws);
        scatter_kernel<<<NCHUNK * NSLICE, 1024, 0, stream>>>(ws);
        kcl_kernel<<<NKCLB, 256, 0, stream>>>(ws);
        final_kernel<<<1, 1024, 0, stream>>>(ws, out);
    } else {
        hipMemsetAsync(d_ws, 0, 256 + (size_t)N_NODES * sizeof(float), stream);
        edge_kernel_fb<<<2048, 256, 0, stream>>>(nf, eidx, logits, params, ws);
        kcl_kernel_fb<<<200, 256, 0, stream>>>(ws);
        final_kernel_fb<<<1, 1, 0, stream>>>(ws, out);
    }
}